// Round 12
// baseline (198.055 us; speedup 1.0000x reference)
//
#include <hip/hip_runtime.h>
#include <stdint.h>

typedef __attribute__((ext_vector_type(8))) short bf16x8;
typedef __attribute__((ext_vector_type(16))) float f32x16;

#define HH  100   // history length
#define DD  128   // embedding dim d
#define HID 256   // hidden width / concat dim

__device__ __forceinline__ unsigned short f2bf(float f) {
    unsigned int u = __float_as_uint(f);
    u += 0x7fffu + ((u >> 16) & 1u);   // round-to-nearest-even
    return (unsigned short)(u >> 16);
}

// async 1 KB global->LDS per wave: per-lane 16 B from g+lane*16, LDS at uniform base + lane*16
__device__ __forceinline__ void load_lds_1k(const void* g, void* l) {
    __builtin_amdgcn_global_load_lds((const __attribute__((address_space(1))) unsigned int*)g,
                                     (__attribute__((address_space(3))) unsigned int*)l,
                                     16, 0, 0);
}

// Pack W1 (256x256 f32, [n][k]) into 32x32x16 MFMA B-fragment order, bf16.
// unit u = (st*16+s)*64 + lane holds W1[st*32 + (lane&31)][s*16 + (lane>>5)*8 + j], j=0..7
__global__ void w1_pack(const float* __restrict__ W1, unsigned short* __restrict__ W1p) {
    int unit = blockIdx.x * 256 + threadIdx.x;   // 0..8191
    int lane = unit & 63;
    int s    = (unit >> 6) & 15;
    int st   = unit >> 10;
    int n    = st * 32 + (lane & 31);
    int k    = s * 16 + (lane >> 5) * 8;
    const float* src = W1 + (size_t)n * HID + k;
    union { unsigned short u[8]; bf16x8 v; } o;
    #pragma unroll
    for (int j = 0; j < 8; j++) o.u[j] = f2bf(src[j]);
    *(bf16x8*)(W1p + (size_t)unit * 8) = o.v;
}

// 256-thread block = 4 waves, one element per block, one 32-row tile per wave
// (32x32x16 MFMA: same 16 B/lane B-read feeds 2x the FLOPs of 16x16x32 ->
// per-element LDS B-traffic halves to 512 KB). (256,2) is the proven
// non-spilling bound family (R3/R5/R7/R10 all spilled under tighter bounds).
__global__ __launch_bounds__(256, 2) void nais_kernel(
    const int* __restrict__ history,           // [B,HH]
    const int* __restrict__ target,            // [B]
    const int* __restrict__ history_region,    // [B,HH]
    const int* __restrict__ target_region,     // [B]
    const float* __restrict__ target_distance, // [B]
    const float* __restrict__ E_hist,          // [item,128]
    const float* __restrict__ E_tgt,           // [item,128]
    const float* __restrict__ E_reg,           // [region,128]
    const float* __restrict__ E_dist,          // [16,128]
    const float* __restrict__ b1,              // [256]
    const float* __restrict__ w2,              // [256]
    const unsigned short* __restrict__ W1p,    // packed bf16 B-fragments (128 KB)
    float* __restrict__ out)                   // [B]
{
    // B-stage: 8 stages x 16 KB (one 32-col strip each), double-buffered = 32 KB
    __shared__ __align__(16) unsigned short Bs[2][8192];
    __shared__ __align__(16) float tgts[HID];
    __shared__ __align__(16) float b1s[HID];
    __shared__ __align__(16) float w2s[HID];
    __shared__ float score[128];
    __shared__ float xsum[128];
    __shared__ float eA[HH];
    __shared__ float exs[HH];
    __shared__ int hidx[HH];
    __shared__ int hreg[HH];
    __shared__ float s_sumE;

    const int b    = blockIdx.x;
    const int t    = threadIdx.x;
    const int lane = t & 63;
    const int wave = t >> 6;                   // 0..3, owns rows 32w..32w+31
    const int m32  = lane & 31;
    const int half = lane >> 5;

    const int   tg    = target[b];
    const float tdist = target_distance[b];

    // ---- phase 0: stage indices, tgt vector, b1/w2, sum(E_dist[0]) ----
    if (t < HH) {
        hidx[t] = history[b * HH + t];
        hreg[t] = history_region[b * HH + t];
    }
    if (wave == 1) {
        float v = E_dist[lane] + E_dist[64 + lane];
        #pragma unroll
        for (int off = 32; off; off >>= 1) v += __shfl_xor(v, off);
        if (lane == 0) s_sumE = v;
    }
    if (wave == 2) {
        float4 v;
        if (lane < 32) v = *(const float4*)(E_tgt + (size_t)tg * DD + lane * 4);
        else           v = *(const float4*)(E_reg + (size_t)target_region[b] * DD + (lane - 32) * 4);
        *(float4*)(tgts + lane * 4) = v;
    }
    if (wave == 3) {
        *(float4*)(b1s + lane * 4) = *(const float4*)(b1 + lane * 4);
        *(float4*)(w2s + lane * 4) = *(const float4*)(w2 + lane * 4);
    }
    __syncthreads();

    // issue stage-0 B load (async; overlaps the gather phase). 16 KB / 4 waves.
    {
        const char* g = (const char*)W1p + wave * 4096 + lane * 16;
        char*       l = (char*)&Bs[0][0] + wave * 4096;
        #pragma unroll
        for (int i = 0; i < 4; i++) load_lds_1k(g + i * 1024, l + i * 1024);
    }

    // ---- phase 1: gather E-row into 32x32x16 A-fragment layout ----
    // row = 32*wave + m32; pad rows 100..127 clamp to row-64 (L2-hot duplicates,
    // never read downstream). Lane holds k = s*16 + half*8 + j (j=0..7);
    // s<8 -> E_hist (k<128), s>=8 -> E_reg. Each row gathered by 2 lanes.
    const int row = wave * 32 + m32;
    const int rc  = (row < HH) ? row : row - 64;
    const int ih  = hidx[rc];
    const int ir  = hreg[rc];
    const float* ph = E_hist + (size_t)ih * DD + half * 8;
    const float* pr = E_reg  + (size_t)ir * DD + half * 8;
    bf16x8 afrag[16];
    float acc = 0.f;
    #pragma unroll
    for (int c = 0; c < 4; c++) {            // chunk: 4 s-steps, 8 float4 in flight
        #pragma unroll
        for (int si = 0; si < 4; si++) {
            const int s = c * 4 + si;
            const float* src = (s < 8) ? (ph + s * 16) : (pr + (s - 8) * 16);
            float4 v0 = *(const float4*)src;
            float4 v1 = *(const float4*)(src + 4);
            const float* tp = tgts + s * 16 + half * 8;
            float4 t0 = *(const float4*)tp, t1 = *(const float4*)(tp + 4);
            float x0 = v0.x * t0.x, x1 = v0.y * t0.y, x2 = v0.z * t0.z, x3 = v0.w * t0.w;
            float x4 = v1.x * t1.x, x5 = v1.y * t1.y, x6 = v1.z * t1.z, x7 = v1.w * t1.w;
            acc += (x0 + x1) + (x2 + x3) + ((x4 + x5) + (x6 + x7));
            union { unsigned short u[8]; bf16x8 v; } fb;
            fb.u[0] = f2bf(x0); fb.u[1] = f2bf(x1); fb.u[2] = f2bf(x2); fb.u[3] = f2bf(x3);
            fb.u[4] = f2bf(x4); fb.u[5] = f2bf(x5); fb.u[6] = f2bf(x6); fb.u[7] = f2bf(x7);
            afrag[s] = fb.v;
        }
        asm volatile("" ::: "memory");       // cap in-flight loads (spill guard)
    }
    // xsum[row]: both k-halves of a row live in lanes m32 and m32+32
    {
        float v = acc;
        v += __shfl_xor(v, 32);
        if (half == 0) xsum[row] = v;        // rows >= HH written, never read
    }

    // ---- phase 2: score = relu(X @ W1^T + b1) . w2 via 32x32x16 MFMA ----
    // stage k = one 32-col strip; barrier-per-stage double buffer.
    float sacc[16] = {};
    #pragma unroll 1
    for (int k = 0; k < 8; k++) {
        __syncthreads();
        if (k < 7) {
            const char* g = (const char*)W1p + (k + 1) * 16384 + wave * 4096 + lane * 16;
            char*       l = (char*)&Bs[(k + 1) & 1][0] + wave * 4096;
            #pragma unroll
            for (int i = 0; i < 4; i++) load_lds_1k(g + i * 1024, l + i * 1024);
        }
        const unsigned short* buf = &Bs[k & 1][0];
        f32x16 acc0 = {};
        #pragma unroll
        for (int s = 0; s < 16; s++) {
            bf16x8 bfrag = *(const bf16x8*)(buf + (s * 64 + lane) * 8);
            acc0 = __builtin_amdgcn_mfma_f32_32x32x16_bf16(afrag[s], bfrag, acc0, 0, 0, 0);
        }
        // epilogue for this strip: col = k*32 + m32
        const float bb = b1s[k * 32 + m32];
        const float ww = w2s[k * 32 + m32];
        #pragma unroll
        for (int r = 0; r < 16; r++) {
            float z = acc0[r] + bb;
            sacc[r] += (z > 0.f) ? z * ww : 0.f;
        }
    }
    // column reduction over the 32 cols (lane bits 0..4)
    #pragma unroll
    for (int r = 0; r < 16; r++) {
        float z = sacc[r];
        z += __shfl_xor(z, 1);
        z += __shfl_xor(z, 2);
        z += __shfl_xor(z, 4);
        z += __shfl_xor(z, 8);
        z += __shfl_xor(z, 16);
        sacc[r] = z;
    }
    if (m32 == 0) {   // lanes 0 and 32: rows (r&3)+8*(r>>2)+4*half
        #pragma unroll
        for (int r = 0; r < 16; r++)
            score[wave * 32 + (r & 3) + 8 * (r >> 2) + 4 * half] = sacc[r];
    }

    __syncthreads();

    // ---- phase 3: masked exp, denom^BETA, weighted sum, sigmoid ----
    const float dist = tdist * s_sumE;
    if (t < HH) {
        float e = (hidx[t] != tg) ? expf(score[t] + dist) : 0.f;
        eA[t]  = e;
        exs[t] = e * xsum[t];
    }
    __syncthreads();
    if (t < 64) {
        float s1 = eA[t]  + ((t + 64 < HH) ? eA[t + 64]  : 0.f);
        float s2 = exs[t] + ((t + 64 < HH) ? exs[t + 64] : 0.f);
        #pragma unroll
        for (int off = 32; off; off >>= 1) {
            s1 += __shfl_xor(s1, off);
            s2 += __shfl_xor(s2, off);
        }
        if (t == 0) {
            float pred = s2 / sqrtf(s1);   // exp_sum^0.5 (BETA=0.5)
            out[b] = 1.f / (1.f + expf(-pred));
        }
    }
}

extern "C" void kernel_launch(void* const* d_in, const int* in_sizes, int n_in,
                              void* d_out, int out_size, void* d_ws, size_t ws_size,
                              hipStream_t stream) {
    const int*   history         = (const int*)d_in[0];
    const int*   target          = (const int*)d_in[1];
    const int*   history_region  = (const int*)d_in[2];
    const int*   target_region   = (const int*)d_in[3];
    const float* target_distance = (const float*)d_in[4];
    const float* E_hist          = (const float*)d_in[5];
    const float* E_tgt           = (const float*)d_in[6];
    const float* E_reg           = (const float*)d_in[7];
    const float* E_dist          = (const float*)d_in[8];
    const float* W1              = (const float*)d_in[9];
    const float* b1              = (const float*)d_in[10];
    const float* w2              = (const float*)d_in[11];

    unsigned short* W1p = (unsigned short*)d_ws;  // 131072 B
    const int B = in_sizes[1];

    w1_pack<<<32, 256, 0, stream>>>(W1, W1p);
    nais_kernel<<<B, 256, 0, stream>>>(history, target, history_region, target_region,
                                       target_distance, E_hist, E_tgt, E_reg, E_dist,
                                       b1, w2, W1p, (float*)d_out);
}